// Round 8
// baseline (20023.433 us; speedup 1.0000x reference)
//
#include <hip/hip_runtime.h>
#include <stdint.h>

typedef unsigned short ushort_t;
typedef unsigned long long u64;
typedef __attribute__((ext_vector_type(8))) short short8;
typedef __attribute__((ext_vector_type(4))) float f32x4;
typedef __attribute__((ext_vector_type(4))) unsigned int u32x4;
typedef __attribute__((ext_vector_type(16))) float f32x16;

#define WS_W0T_HI 0u
#define WS_W0T_LO (2u<<20)
#define WS_WST_HI (4u<<20)
#define WS_WST_LO (12u<<20)
#define WS_ST     (20u<<20)
#define WS_BAR    (26u<<20)

#define SLOT_ELEMS 262144   // per state slot (hi+lo bf16 planes), elements
#define PLANE 131072        // 256*512
#define PSTR 536            // full-panel row stride (shorts)
#define PSTR2 268           // half-panel row stride (shorts); 32*268=8576/plane

// state slots (bf16 hi/lo planes): 0=h, 1=s0, 2=s1, 3=s2, 4=s3, 5=s5

__device__ __forceinline__ ushort_t f2bf(float f) {
  unsigned u = __float_as_uint(f);
  u += 0x7FFFu + ((u >> 16) & 1u);          // RNE to bf16
  return (ushort_t)(u >> 16);
}
__device__ __forceinline__ float bf2f(ushort_t h) {
  return __uint_as_float(((unsigned)h) << 16);
}
__device__ __forceinline__ float sigf(float v) { return 1.f / (1.f + __expf(-v)); }

// 16B uncached load (bypass L1/L2, coherent at L3)
__device__ __forceinline__ u32x4 uld16(const void* p) {
  u32x4 r;
  asm volatile("global_load_dwordx4 %0, %1, off sc0 sc1" : "=v"(r) : "v"(p));
  return r;
}

// paired-column state store (uncached 4B words)
__device__ __forceinline__ void st_state(ushort_t* slot, int eo, float s, int tid) {
  ushort_t hi = f2bf(s);
  ushort_t lo = f2bf(s - bf2f(hi));
  unsigned nh = __shfl_xor((unsigned)hi, 1, 64);
  unsigned nl = __shfl_xor((unsigned)lo, 1, 64);
  if (!(tid & 1)) {
    unsigned wh = (unsigned)hi | (nh << 16);
    unsigned wl = (unsigned)lo | (nl << 16);
    __hip_atomic_store((unsigned*)(slot + eo), wh, __ATOMIC_RELAXED, __HIP_MEMORY_SCOPE_AGENT);
    __hip_atomic_store((unsigned*)(slot + PLANE + eo), wl, __ATOMIC_RELAXED, __HIP_MEMORY_SCOPE_AGENT);
  }
}

// convert 8 f32 (plain cached loads) -> bf16 hi/lo fragments (stage A x-path)
__device__ __forceinline__ void xcvt(const float* xp, short8& ah, short8& al) {
  f32x4 v0 = *(const f32x4*)xp;
  f32x4 v1 = *(const f32x4*)(xp + 4);
#pragma unroll
  for (int i = 0; i < 4; ++i) {
    ushort_t h0 = f2bf(v0[i]);
    ah[i] = (short)h0; al[i] = (short)f2bf(v0[i] - bf2f(h0));
    ushort_t h1 = f2bf(v1[i]);
    ah[i + 4] = (short)h1; al[i + 4] = (short)f2bf(v1[i] - bf2f(h1));
  }
}

// ---------------- prep: transpose + hi/lo split weights; convert h0 ---------
extern "C" __global__ void prep_kernel(const float* __restrict__ W0,
                                       const float* __restrict__ Ws,
                                       const float* __restrict__ h0,
                                       char* __restrict__ ws) {
  ushort_t* w0h = (ushort_t*)(ws + WS_W0T_HI);
  ushort_t* w0l = (ushort_t*)(ws + WS_W0T_LO);
  ushort_t* wsh = (ushort_t*)(ws + WS_WST_HI);
  ushort_t* wsl = (ushort_t*)(ws + WS_WST_LO);
  ushort_t* st  = (ushort_t*)(ws + WS_ST);
  const long N0 = 1048576, N1 = 4194304, N2 = 131072;
  long total = N0 + N1 + N2;
  for (long idx = (long)blockIdx.x * blockDim.x + threadIdx.x; idx < total;
       idx += (long)gridDim.x * blockDim.x) {
    if (idx < N0) {                       // W0T[j][k] from W0[k][j], K=1024
      int k = (int)(idx >> 10), j = (int)(idx & 1023);
      float v = W0[k * 1024 + j];
      ushort_t hi = f2bf(v);
      w0h[j * 1024 + k] = hi;
      w0l[j * 1024 + k] = f2bf(v - bf2f(hi));
    } else if (idx < N0 + N1) {           // WsT[i][j][k] from Ws[i][k][j], K=512
      long r = idx - N0;
      int i = (int)(r >> 19);
      int r2 = (int)(r & 524287);
      int k = r2 >> 10, j = r2 & 1023;
      float v = Ws[(long)i * 524288 + k * 1024 + j];
      ushort_t hi = f2bf(v);
      wsh[(long)i * 524288 + j * 512 + k] = hi;
      wsl[(long)i * 524288 + j * 512 + k] = f2bf(v - bf2f(hi));
    } else {                              // h0 -> slot 0
      int e = (int)(idx - N0 - N1);
      float v = h0[e];
      ushort_t hi = f2bf(v);
      st[0 * SLOT_ELEMS + e] = hi;
      st[0 * SLOT_ELEMS + PLANE + e] = f2bf(v - bf2f(hi));
    }
  }
}

// ---- producer-flag sync: set after this WG's stores are drained -----------
__device__ __forceinline__ void set_flag(unsigned* flags, int g, int pt, unsigned gen) {
  __syncthreads();   // per-wave vmcnt(0) drain: uncached stores at coherence point
  if (threadIdx.x == 0)
    __hip_atomic_store(flags + (g * 32 + pt) * 16, gen, __ATOMIC_RELAXED, __HIP_MEMORY_SCOPE_AGENT);
}

// ---- full-panel load: poll 2 producers, then bulk 16B uncached -------------
// thread (row=tid>>4, i=tid&15) loads cols [i*16,+16) and [256+i*16,+16)
// (producers i and i+16). 16B chunks at 32B lane-stride -> 4-way write banks.
__device__ __forceinline__ void panel_load(const ushort_t* slot, int r0,
                                           ushort_t* Ah, ushort_t* Al,
                                           const unsigned* flags, int g, unsigned G,
                                           int tid) {
  const int row = tid >> 4, i = tid & 15;
  const unsigned* f0 = flags + (g * 32 + i) * 16;
  const unsigned* f1 = flags + (g * 32 + 16 + i) * 16;
  while (__hip_atomic_load(f0, __ATOMIC_RELAXED, __HIP_MEMORY_SCOPE_AGENT) < G)
    __builtin_amdgcn_s_sleep(2);
  while (__hip_atomic_load(f1, __ATOMIC_RELAXED, __HIP_MEMORY_SCOPE_AGENT) < G)
    __builtin_amdgcn_s_sleep(2);
  const ushort_t* src = slot + (r0 + row) * 512;
  const int c0 = i * 16, c1 = 256 + i * 16;
  u32x4 v0 = uld16(src + c0), v1 = uld16(src + c0 + 8);
  u32x4 v2 = uld16(src + c1), v3 = uld16(src + c1 + 8);
  u32x4 v4 = uld16(src + PLANE + c0), v5 = uld16(src + PLANE + c0 + 8);
  u32x4 v6 = uld16(src + PLANE + c1), v7 = uld16(src + PLANE + c1 + 8);
  asm volatile("s_waitcnt vmcnt(0)" ::: "memory");
  __builtin_amdgcn_sched_barrier(0);      // rule #18: pin consumers after waitcnt
  const int o0 = row * PSTR + c0, o1 = row * PSTR + c1;
  *(u32x4*)(Ah + o0) = v0; *(u32x4*)(Ah + o0 + 8) = v1;
  *(u32x4*)(Ah + o1) = v2; *(u32x4*)(Ah + o1 + 8) = v3;
  *(u32x4*)(Al + o0) = v4; *(u32x4*)(Al + o0 + 8) = v5;
  *(u32x4*)(Al + o1) = v6; *(u32x4*)(Al + o1 + 8) = v7;
}

__device__ __forceinline__ f32x16 mfma3(short8 ah, short8 al, short8 bh, short8 bl, f32x16 acc) {
  acc = __builtin_amdgcn_mfma_f32_32x32x16_bf16(ah, bh, acc, 0, 0, 0);
  acc = __builtin_amdgcn_mfma_f32_32x32x16_bf16(ah, bl, acc, 0, 0, 0);
  acc = __builtin_amdgcn_mfma_f32_32x32x16_bf16(al, bh, acc, 0, 0, 0);
  return acc;
}

// matmul vs NP weight matrices; A-frags from LDS panel (XA: first 512 K from x)
template<int NP, int NBLK, bool XA>
__device__ __forceinline__ void mm_lds(const ushort_t* Ah, const ushort_t* Al,
                                       const float* xrow,
                                       const ushort_t* const (&bh)[NP],
                                       const ushort_t* const (&bl)[NP],
                                       int boff, int kw, int lr,
                                       f32x16 (&acc)[NP]) {
#pragma unroll
  for (int j = 0; j < NBLK; ++j) {
    int kq = j * 128 + kw;
    short8 a_h, a_l;
    if (XA && j < 4) {
      xcvt(xrow + kq, a_h, a_l);
    } else {
      int kp = XA ? (kq - 512) : kq;
      a_h = *(const short8*)(Ah + lr * PSTR + kp);
      a_l = *(const short8*)(Al + lr * PSTR + kp);
    }
#pragma unroll
    for (int p = 0; p < NP; ++p) {
      short8 b_h = *(const short8*)(bh[p] + boff + kq);
      short8 b_l = *(const short8*)(bl[p] + boff + kq);
      acc[p] = mfma3(a_h, a_l, b_h, b_l, acc[p]);
    }
  }
}

// stage-D half-K matmul: s2 half-panel in B2 (hi/lo at 0/8576), s3 in B3
__device__ __forceinline__ void mmD(const ushort_t* B2, const ushort_t* B3,
                                    const ushort_t* wah, const ushort_t* wal,
                                    const ushort_t* wbh, const ushort_t* wbl,
                                    int b512, int h, int w, int lane,
                                    f32x16& acc5, f32x16& acc7) {
  const int lr = lane & 31;
  const int bkk = (lane >> 5) * 8;
  const int ak = lr * PSTR2 + bkk;
#pragma unroll
  for (int s = 0; s < 2; ++s) {
    const int kl = w * 32 + s * 16;
    const int kq = h * 256 + kl + bkk;
    short8 a2h = *(const short8*)(B2 + ak + kl);
    short8 a2l = *(const short8*)(B2 + 8576 + ak + kl);
    short8 a3h = *(const short8*)(B3 + ak + kl);
    short8 a3l = *(const short8*)(B3 + 8576 + ak + kl);
    short8 bah = *(const short8*)(wah + b512 + kq);
    short8 bal = *(const short8*)(wal + b512 + kq);
    short8 bbh = *(const short8*)(wbh + b512 + kq);
    short8 bbl = *(const short8*)(wbl + b512 + kq);
    acc5 = mfma3(a2h, a2l, bah, bal, acc5);
    acc7 = mfma3(a3h, a3l, bbh, bbl, acc7);
  }
}

__device__ __forceinline__ void wr_pp1(float* pp, const f32x16& a, int w, int lane) {
  int col = lane & 31, h5 = lane >> 5;
  float* base = pp + w * 1056 + col;
#pragma unroll
  for (int r = 0; r < 16; ++r) {
    int row = (r & 3) + 8 * (r >> 2) + 4 * h5;   // verified 32x32 C/D layout
    base[row * 33] = a[r];
  }
}
__device__ __forceinline__ void rd_pp1(const float* pp, int row, int cp,
                                       float& c, float& h) {
  float cs = 0.f, hs = 0.f;
#pragma unroll
  for (int w = 0; w < 8; ++w) {
    cs += pp[w * 1056 + row * 33 + cp];
    hs += pp[w * 1056 + row * 33 + cp + 16];
  }
  c = cs; h = hs;
}

// ---------------- main persistent cooperative kernel -----------------------
extern "C" __global__ void __launch_bounds__(512, 1)
rnn_main(const float* __restrict__ x, float* __restrict__ out, char* __restrict__ ws) {
  __shared__ __align__(16) ushort_t Ah[32 * PSTR];  // 34.3 KB panel hi / D: s2 halves
  __shared__ __align__(16) ushort_t Al[32 * PSTR];  // 34.3 KB panel lo / D: s3 halves
  __shared__ float pp[8 * 1056];          // 33.8 KB wave partials

  ushort_t* stg = (ushort_t*)(ws + WS_ST);
  unsigned* flags = (unsigned*)(ws + WS_BAR);
  const ushort_t* w0h = (const ushort_t*)(ws + WS_W0T_HI);
  const ushort_t* w0l = (const ushort_t*)(ws + WS_W0T_LO);
  const ushort_t* wsh = (const ushort_t*)(ws + WS_WST_HI);
  const ushort_t* wsl = (const ushort_t*)(ws + WS_WST_LO);

  const int tid = threadIdx.x;
  const int wg = blockIdx.x;
  const int rt = wg >> 5, pt = wg & 31;   // 8 row-groups x 32 col-WGs; XCD=pt%8 (perf)
  const int g = rt, r0 = rt * 32;
  const int w = tid >> 6, lane = tid & 63;
  const int kw = w * 16 + (lane >> 5) * 8;
  const int lr = lane & 31;
  const int jc = pt * 16 + (lr & 15) + (lr >> 4) * 512;  // weight col for B-frags
  const int b512 = jc * 512, b1024 = jc * 1024;
  const int erow = tid >> 4, ecp = tid & 15;
  const int scol = pt * 16 + ecp;
  const int eo = (r0 + erow) * 512 + scol;
  const int spo = erow * PSTR + scol;

  float sumreg = 0.f;

  for (int t = 0; t < 400; ++t) {
    const unsigned base = 5u * (unsigned)t;
    const float* xrow = x + (size_t)t * 131072 + (size_t)(r0 + lr) * 512;

    // ---- stage A: s0 = h + sig(c)*(tanh(h) - h), A=[x|h], W0 (K=1024) -----
    panel_load(stg + 0 * SLOT_ELEMS, r0, Ah, Al, flags, g, base, tid);
    __syncthreads();
    {
      f32x16 acc[1] = {};
      const ushort_t* bh[1] = {w0h};
      const ushort_t* bl[1] = {w0l};
      mm_lds<1, 8, true>(Ah, Al, xrow, bh, bl, b1024, kw, lr, acc);
      __syncthreads();
      wr_pp1(pp, acc[0], w, lane);
      __syncthreads();
      float c, hh; rd_pp1(pp, erow, ecp, c, hh);
      float sp = bf2f(Ah[spo]) + bf2f(Al[spo]);
      float s = sp + sigf(c) * (tanhf(hh) - sp);
      st_state(stg + 1 * SLOT_ELEMS, eo, s, tid);
    }
    set_flag(flags, g, pt, base + 1);

    // ---- stage B: s1 = f(s0, tanh, Ws[0]) ---------------------------------
    panel_load(stg + 1 * SLOT_ELEMS, r0, Ah, Al, flags, g, base + 1, tid);
    __syncthreads();
    {
      f32x16 acc[1] = {};
      const ushort_t* bh[1] = {wsh + 0 * 524288};
      const ushort_t* bl[1] = {wsl + 0 * 524288};
      mm_lds<1, 4, false>(Ah, Al, nullptr, bh, bl, b512, kw, lr, acc);
      __syncthreads();
      wr_pp1(pp, acc[0], w, lane);
      __syncthreads();
      float c, hh; rd_pp1(pp, erow, ecp, c, hh);
      float sp = bf2f(Ah[spo]) + bf2f(Al[spo]);
      float s = sp + sigf(c) * (tanhf(hh) - sp);
      sumreg += s;
      st_state(stg + 2 * SLOT_ELEMS, eo, s, tid);
    }
    set_flag(flags, g, pt, base + 2);

    // ---- stage C: s2(relu) s3(relu) s4(ident) from s1, Ws[1..3] -----------
    panel_load(stg + 2 * SLOT_ELEMS, r0, Ah, Al, flags, g, base + 2, tid);
    __syncthreads();
    {
      f32x16 acc[3] = {};
      const ushort_t* bh[3] = {wsh + 1 * 524288, wsh + 2 * 524288, wsh + 3 * 524288};
      const ushort_t* bl[3] = {wsl + 1 * 524288, wsl + 2 * 524288, wsl + 3 * 524288};
      mm_lds<3, 4, false>(Ah, Al, nullptr, bh, bl, b512, kw, lr, acc);
      float sp;
      __syncthreads();
      wr_pp1(pp, acc[0], w, lane);        // s2 -> slot3
      __syncthreads();
      {
        float c, hh; rd_pp1(pp, erow, ecp, c, hh);
        sp = bf2f(Ah[spo]) + bf2f(Al[spo]);
        float s = sp + sigf(c) * (fmaxf(hh, 0.f) - sp);
        sumreg += s;
        st_state(stg + 3 * SLOT_ELEMS, eo, s, tid);
      }
      __syncthreads();
      wr_pp1(pp, acc[1], w, lane);        // s3 -> slot4
      __syncthreads();
      {
        float c, hh; rd_pp1(pp, erow, ecp, c, hh);
        float s = sp + sigf(c) * (fmaxf(hh, 0.f) - sp);
        sumreg += s;
        st_state(stg + 4 * SLOT_ELEMS, eo, s, tid);
      }
      set_flag(flags, g, pt, base + 3);   // early: D only needs s2/s3
      wr_pp1(pp, acc[2], w, lane);        // s4: concat-only
      __syncthreads();
      {
        float c, hh; rd_pp1(pp, erow, ecp, c, hh);
        sumreg += sp + sigf(c) * (hh - sp);
      }
    }

    // ---- stage D (merged): s5 = f(s2,tanh,Ws[4]); s7 = f(s3,tanh,Ws[6]) ---
    // two half-K passes; half-1 global loads issued during half-0 MFMA.
    {
      const int i = tid & 15;
      const unsigned G3 = base + 3;
      const unsigned* f0 = flags + (g * 32 + i) * 16;
      const unsigned* f1 = flags + (g * 32 + 16 + i) * 16;
      while (__hip_atomic_load(f0, __ATOMIC_RELAXED, __HIP_MEMORY_SCOPE_AGENT) < G3)
        __builtin_amdgcn_s_sleep(2);
      while (__hip_atomic_load(f1, __ATOMIC_RELAXED, __HIP_MEMORY_SCOPE_AGENT) < G3)
        __builtin_amdgcn_s_sleep(2);
      const int prow = tid >> 4;
      const ushort_t* s2p = stg + 3 * SLOT_ELEMS + (r0 + prow) * 512;
      const ushort_t* s3p = stg + 4 * SLOT_ELEMS + (r0 + prow) * 512;
      const int po = prow * PSTR2 + i * 16;
      {                                   // half 0 load -> LDS
        u32x4 v0 = uld16(s2p + i * 16),        v1 = uld16(s2p + i * 16 + 8);
        u32x4 v2 = uld16(s2p + PLANE + i * 16), v3 = uld16(s2p + PLANE + i * 16 + 8);
        u32x4 q0 = uld16(s3p + i * 16),        q1 = uld16(s3p + i * 16 + 8);
        u32x4 q2 = uld16(s3p + PLANE + i * 16), q3 = uld16(s3p + PLANE + i * 16 + 8);
        asm volatile("s_waitcnt vmcnt(0)" ::: "memory");
        __builtin_amdgcn_sched_barrier(0);
        *(u32x4*)(Ah + po) = v0;        *(u32x4*)(Ah + po + 8) = v1;
        *(u32x4*)(Ah + 8576 + po) = v2; *(u32x4*)(Ah + 8576 + po + 8) = v3;
        *(u32x4*)(Al + po) = q0;        *(u32x4*)(Al + po + 8) = q1;
        *(u32x4*)(Al + 8576 + po) = q2; *(u32x4*)(Al + 8576 + po + 8) = q3;
      }
      __syncthreads();
      const int hstar = pt >> 4;
      const int lcs = erow * PSTR2 + ((pt & 15) * 16 + ecp);
      float sp2 = 0.f, sp3 = 0.f;
      if (hstar == 0) {
        sp2 = bf2f(Ah[lcs]) + bf2f(Ah[8576 + lcs]);
        sp3 = bf2f(Al[lcs]) + bf2f(Al[8576 + lcs]);
      }
      // issue half-1 loads: land during half-0 MFMA
      u32x4 y0 = uld16(s2p + 256 + i * 16),        y1 = uld16(s2p + 256 + i * 16 + 8);
      u32x4 y2 = uld16(s2p + PLANE + 256 + i * 16), y3 = uld16(s2p + PLANE + 256 + i * 16 + 8);
      u32x4 z0 = uld16(s3p + 256 + i * 16),        z1 = uld16(s3p + 256 + i * 16 + 8);
      u32x4 z2 = uld16(s3p + PLANE + 256 + i * 16), z3 = uld16(s3p + PLANE + 256 + i * 16 + 8);
      f32x16 acc5 = {}, acc7 = {};
      mmD(Ah, Al, wsh + 4 * 524288, wsl + 4 * 524288,
          wsh + 6 * 524288, wsl + 6 * 524288, b512, 0, w, lane, acc5, acc7);
      __syncthreads();                    // all half-0 reads done; drains vmcnt
      asm volatile("s_waitcnt vmcnt(0)" ::: "memory");
      __builtin_amdgcn_sched_barrier(0);
      *(u32x4*)(Ah + po) = y0;        *(u32x4*)(Ah + po + 8) = y1;
      *(u32x4*)(Ah + 8576 + po) = y2; *(u32x4*)(Ah + 8576 + po + 8) = y3;
      *(u32x4*)(Al + po) = z0;        *(u32x4*)(Al + po + 8) = z1;
      *(u32x4*)(Al + 8576 + po) = z2; *(u32x4*)(Al + 8576 + po + 8) = z3;
      __syncthreads();
      if (hstar == 1) {
        sp2 = bf2f(Ah[lcs]) + bf2f(Ah[8576 + lcs]);
        sp3 = bf2f(Al[lcs]) + bf2f(Al[8576 + lcs]);
      }
      mmD(Ah, Al, wsh + 4 * 524288, wsl + 4 * 524288,
          wsh + 6 * 524288, wsl + 6 * 524288, b512, 1, w, lane, acc5, acc7);
      __syncthreads();
      wr_pp1(pp, acc5, w, lane);          // s5
      __syncthreads();
      {
        float c, hh; rd_pp1(pp, erow, ecp, c, hh);
        float s5v = sp2 + sigf(c) * (tanhf(hh) - sp2);
        sumreg += s5v;
        st_state(stg + 5 * SLOT_ELEMS, eo, s5v, tid);
      }
      set_flag(flags, g, pt, base + 4);   // s5 visible; also fences pp reuse
      wr_pp1(pp, acc7, w, lane);          // s7: concat-only
      __syncthreads();
      {
        float c, hh; rd_pp1(pp, erow, ecp, c, hh);
        sumreg += sp3 + sigf(c) * (tanhf(hh) - sp3);
      }
    }

    // ---- stage E: s6(sigmoid,Ws[5]) s8(relu,Ws[7]) from s5; mean; h -------
    __syncthreads();
    panel_load(stg + 5 * SLOT_ELEMS, r0, Ah, Al, flags, g, base + 4, tid);
    __syncthreads();
    {
      f32x16 acc[2] = {};
      const ushort_t* bh[2] = {wsh + 5 * 524288, wsh + 7 * 524288};
      const ushort_t* bl[2] = {wsl + 5 * 524288, wsl + 7 * 524288};
      mm_lds<2, 4, false>(Ah, Al, nullptr, bh, bl, b512, kw, lr, acc);
      __syncthreads();
      wr_pp1(pp, acc[0], w, lane);        // s6
      __syncthreads();
      float sp = bf2f(Ah[spo]) + bf2f(Al[spo]);
      {
        float c, hh; rd_pp1(pp, erow, ecp, c, hh);
        sumreg += sp + sigf(c) * (sigf(hh) - sp);
      }
      __syncthreads();
      wr_pp1(pp, acc[1], w, lane);        // s8
      __syncthreads();
      {
        float c, hh; rd_pp1(pp, erow, ecp, c, hh);
        sumreg += sp + sigf(c) * (fmaxf(hh, 0.f) - sp);
      }
      float hn = sumreg * 0.125f;
      __builtin_nontemporal_store(hn, &out[(size_t)t * 131072 + eo]);
      if (t == 399)
        __builtin_nontemporal_store(hn, &out[(size_t)400 * 131072 + eo]);
      st_state(stg + 0 * SLOT_ELEMS, eo, hn, tid);
      sumreg = 0.f;
    }
    set_flag(flags, g, pt, base + 5);
  }
}

// ---------------- host launch ----------------------------------------------
extern "C" void kernel_launch(void* const* d_in, const int* in_sizes, int n_in,
                              void* d_out, int out_size, void* d_ws, size_t ws_size,
                              hipStream_t stream) {
  const float* x  = (const float*)d_in[0];
  const float* h0 = (const float*)d_in[1];
  const float* W0 = (const float*)d_in[2];
  const float* Ws = (const float*)d_in[3];
  float* out = (float*)d_out;
  char* ws = (char*)d_ws;

  (void)in_sizes; (void)n_in; (void)out_size; (void)ws_size;

  (void)hipMemsetAsync(ws + WS_BAR, 0, 16384, stream);
  hipLaunchKernelGGL(prep_kernel, dim3(2048), dim3(256), 0, stream, W0, Ws, h0, ws);

  void* args[3] = {(void*)&x, (void*)&out, (void*)&ws};
  (void)hipLaunchCooperativeKernel((void*)rnn_main, dim3(256), dim3(512), args, 0, stream);
}